// Round 9
// baseline (598.142 us; speedup 1.0000x reference)
//
#include <hip/hip_runtime.h>
#include <hip/hip_fp16.h>

typedef float v2f __attribute__((ext_vector_type(2)));
typedef float v4f __attribute__((ext_vector_type(4)));
typedef int   v4i __attribute__((ext_vector_type(4)));

__device__ __constant__ float GC[16][4] = {
  {0,0,0,0},{0,0,0,1},{0,1,0,-1},{0,1,0,0},
  {0,0,1,-1},{0,0,1,0},{0,1,1,-2},{0,1,1,-1},
  {1,-1,-1,1},{1,-1,-1,2},{1,0,-1,0},{1,0,-1,1},
  {1,-1,0,0},{1,-1,0,1},{1,0,0,-1},{1,0,0,0}};

// ---- packed fp32 helpers (V_PK_FMA/MUL exist on gfx950) ----
__device__ __forceinline__ v2f pk_mul(v2f a, v2f b) {
  v2f d;
  asm("v_pk_mul_f32 %0, %1, %2" : "=v"(d) : "v"(a), "v"(b));
  return d;
}
// r = w0 + w1*a + w2*b + w3*(a*b), per half; w01=(w0,w1) pair, w23=(w2,w3).
__device__ __forceinline__ v2f gate2pk(v2f a, v2f b, v2f w01, v2f w23) {
  v2f t = pk_mul(a, b);
  v2f d;
  asm("v_pk_fma_f32 %0, %1, %2, %2 op_sel:[0,1,0] op_sel_hi:[1,1,0]"
      : "=v"(d) : "v"(a), "v"(w01));
  asm("v_pk_fma_f32 %0, %1, %2, %0 op_sel:[0,0,0] op_sel_hi:[1,0,1]"
      : "+v"(d) : "v"(b), "v"(w23));
  asm("v_pk_fma_f32 %0, %1, %2, %0 op_sel:[0,1,0] op_sel_hi:[1,1,1]"
      : "+v"(d) : "v"(t), "v"(w23));
  return d;
}

__device__ __forceinline__ void mix_one(const float* lp, float* op) {
  float e[16];
  float s = 0.f;
  #pragma unroll
  for (int i = 0; i < 16; ++i) { e[i] = __expf(lp[i]); s += e[i]; }
  float inv = 1.0f / s;
  float w0 = 0.f, w1 = 0.f, w2 = 0.f, w3 = 0.f;
  #pragma unroll
  for (int i = 0; i < 16; ++i) {
    float p = e[i] * inv;
    w0 = fmaf(p, GC[i][0], w0);
    w1 = fmaf(p, GC[i][1], w1);
    w2 = fmaf(p, GC[i][2], w2);
    w3 = fmaf(p, GC[i][3], w3);
  }
  op[0] = w0; op[1] = w1; op[2] = w2; op[3] = w3;
}

struct PrepArgs {
  const float* logits[7];
  float* outm[7];
  const int* cidx[4];
  int* offt[4];
  int* flags;
};

// gid 0..83551: weight softmax-mix. gid 83552..85247: leaf-offset decode.
// gid 85248..86271: zero pair-sync flags (128 pairs x 8).
__global__ __launch_bounds__(256) void prep_k(PrepArgs A) {
  int gid = blockIdx.x * 256 + threadIdx.x;
  if (gid < 83552) {
    const int n[7] = {224, 896, 3584, 7168, 40960, 20480, 10240};
    int g = gid, seg = 0;
    while (seg < 6 && g >= n[seg]) { g -= n[seg]; ++seg; }
    mix_one(A.logits[seg] + (size_t)g * 16, A.outm[seg] + (size_t)g * 4);
  } else if (gid < 85248) {
    int r = gid - 83552;
    int L, rr;
    if (r < 32)       { L = 0; rr = r;       }
    else if (r < 160) { L = 1; rr = r - 32;  }
    else if (r < 672) { L = 2; rr = r - 160; }
    else              { L = 3; rr = r - 672; }
    const int W2Pt[4] = {35, 19, 12, 6};
    const int CSt[4]  = {1190, 342, 121, 37};
    const int swzt[4] = {1, 1, 1, 0};
    int W2P = W2Pt[L], CS = CSt[L], swz = swzt[L];
    const int* ci = A.cidx[L] + rr * 8;
    int* oo = A.offt[L] + rr * 8;
    #pragma unroll
    for (int l = 0; l < 8; ++l) {
      int idx = ci[l];
      int c  = idx / 9;
      int k  = idx - 9 * c;
      int di = k / 3 - 1;
      int dj = k - 3 * (k / 3) - 1;
      int yl = 1 + di;                      // 0..2
      int off = c * CS + yl * W2P + 1 + dj;
      if (swz)
        off |= (((yl >> 1) & 1) << 28) | ((((yl + 1) >> 1) & 1) << 29);
      oo[l] = off;
    }
  } else if (gid < 86272) {
    A.flags[gid - 85248] = 0;
  }
}

struct MegaArgs {
  const float* x;
  const float* mc[4];
  const int*   offt[4];
  const int*   la[3];
  const int*   lb[3];
  const float* mlw[3];
  int*   flags;    // [128][8]
  float* ex;       // [128][46080] exchange arena
  float* out;
};

extern __shared__ char S[];

// Conv+or_pool on the block's row-half. ph0 = row offset of this half.
template<int OWF, int LOGOW, int IW2P, int PIXH, int LOGPIXH,
         int NCH, int ITERS, bool UNI, bool RSWZ, bool OHALO, int OW2P,
         int OCS, bool OSWZ, int OHW>
__device__ __forceinline__ void conv_stage(
    const float* in, float* outb,
    const int* __restrict__ offt, const float* __restrict__ mtab,
    int tid, int ph0) {
  int pix = tid & (PIXH - 1);
  int ch0 = tid >> LOGPIXH;
  int pw  = pix & (OWF - 1);
  int ph  = (pix >> LOGOW) + ph0;
  int pixbase = 2 * ph * IW2P + 2 * pw;
  int ph1 = ph & 1;
  #pragma unroll 4
  for (int it = 0; it < ITERS; ++it) {
    int ch = ch0 + NCH * it;
    if (UNI) ch = __builtin_amdgcn_readfirstlane(ch);
    const int* ot = offt + ch * 8;
    const float* mt = mtab + ch * 28;
    v4f g0 = *(const v4f*)(mt +  0);
    v4f g1 = *(const v4f*)(mt +  4);
    v4f g2 = *(const v4f*)(mt +  8);
    v4f g3 = *(const v4f*)(mt + 12);
    v4f g4 = *(const v4f*)(mt + 16);
    v4f g5 = *(const v4f*)(mt + 20);
    v4f g6 = *(const v4f*)(mt + 24);
    v2f v01[8], v23[8];
    #pragma unroll
    for (int l = 0; l < 8; ++l) {
      int e = ot[l];
      int at, ab;
      if (RSWZ) {
        int off = e & 0x0FFFFFFF;
        at = off + pixbase + ((ph1 ^ (e >> 28)) & 1);
        ab = off + pixbase + IW2P + ((ph1 ^ (e >> 29)) & 1);
      } else {
        at = e + pixbase;
        ab = at + IW2P;
      }
      v2f t0; t0.x = in[at]; t0.y = in[at + 1];
      v2f t1; t1.x = in[ab]; t1.y = in[ab + 1];
      v01[l] = t0; v23[l] = t1;
    }
    v2f u0 = gate2pk(v01[0], v01[1], g0.xy, g0.zw);
    v2f u1 = gate2pk(v01[2], v01[3], g1.xy, g1.zw);
    v2f u2 = gate2pk(v01[4], v01[5], g2.xy, g2.zw);
    v2f u3 = gate2pk(v01[6], v01[7], g3.xy, g3.zw);
    v2f s0 = gate2pk(u0, u1, g4.xy, g4.zw);
    v2f s1 = gate2pk(u2, u3, g5.xy, g5.zw);
    v2f r0 = gate2pk(s0, s1, g6.xy, g6.zw);
    u0 = gate2pk(v23[0], v23[1], g0.xy, g0.zw);
    u1 = gate2pk(v23[2], v23[3], g1.xy, g1.zw);
    u2 = gate2pk(v23[4], v23[5], g2.xy, g2.zw);
    u3 = gate2pk(v23[6], v23[7], g3.xy, g3.zw);
    s0 = gate2pk(u0, u1, g4.xy, g4.zw);
    s1 = gate2pk(u2, u3, g5.xy, g5.zw);
    v2f r1 = gate2pk(s0, s1, g6.xy, g6.zw);
    float res = fmaxf(fmaxf(r0.x, r0.y), fmaxf(r1.x, r1.y));
    if (OHALO) {
      int oy = 1 + ph;
      int widx = ch * OCS + oy * OW2P + 1 + pw;
      if (OSWZ) widx += (oy >> 1) & 1;
      outb[widx] = res;
    } else {
      outb[ch * OHW + ph * OWF + pw] = res;
    }
  }
}

__device__ __forceinline__ void sigf(int* f) {
  if (threadIdx.x == 0)
    __hip_atomic_fetch_add(f, 1, __ATOMIC_RELEASE, __HIP_MEMORY_SCOPE_AGENT);
}
__device__ __forceinline__ void waitf(int* f, int v) {
  if (threadIdx.x == 0)
    while (__hip_atomic_load(f, __ATOMIC_ACQUIRE, __HIP_MEMORY_SCOPE_AGENT) < v)
      __builtin_amdgcn_s_sleep(8);
}

// LDS layout (bytes), regions A@0 (61952) and B@61952:
//  binb [9][34][35]+pad @ A      (42848)
//  buf1 [32][342]       @ B      (43776)
//  buf2 [128][121]      @ A      (61952)
//  buf3 [512][37]       @ B      (75776)  ends 137728
//  h4   [4096] f32      @ 0      (16384)
//  g1h  [40960] f16     @ 16384  ends 98304
//  g2h  [20480] f16     @ 98304  ends 139264
//  lsum [10] f32        @ 139264
// Grid 256: block = (batch b = blockIdx&127, half h = blockIdx>>7).
__global__ __launch_bounds__(1024) void mega_k(MegaArgs A) {
  int tid = threadIdx.x;
  int b = blockIdx.x & 127;
  int h = blockIdx.x >> 7;
  int hp = 1 - h;
  float* binb = (float*)(S);
  float* buf1 = (float*)(S + 61952);
  float* buf2 = (float*)(S);
  float* buf3 = (float*)(S + 61952);
  float* h4   = (float*)(S);
  __half* g1h = (__half*)(S + 16384);
  __half* g2h = (__half*)(S + 98304);
  float* lsum = (float*)(S + 139264);
  const v4f z4 = {0.f, 0.f, 0.f, 0.f};

  int*   flg = A.flags + b * 8;
  float* exb = A.ex + (size_t)b * 46080;
  float* e1g  = exb;             // 2*608
  float* e2g  = exb + 1216;      // 2*1536
  float* e3g  = exb + 4288;      // 2*3072
  float* e4g  = exb + 10432;     // 2*2048
  float* eg1g = exb + 14528;     // 2*10240
  float* eg2g = exb + 35008;     // 2*5120   (ends 45248)

  // ---- binarize (both halves compute the full input) ----
  for (int i = 4 * tid; i < 10712; i += 4096) *(v4f*)(binb + i) = z4;
  if (tid < 10) lsum[tid] = 0.f;
  __syncthreads();
  const float* xb = A.x + (size_t)b * 3072;
  #pragma unroll
  for (int i = 0; i < 3; ++i) {
    int idx = tid + 1024 * i;
    float v = xb[idx];
    int rgb = idx >> 10;
    int rem = idx & 1023;
    int y = rem >> 5, xx = rem & 31;
    int oy = 1 + y;
    int base = oy * 35 + 1 + xx + ((oy >> 1) & 1);
    binb[(0 + rgb) * 1190 + base] = v > 0.25f ? 1.f : 0.f;
    binb[(3 + rgb) * 1190 + base] = v > 0.50f ? 1.f : 0.f;
    binb[(6 + rgb) * 1190 + base] = v > 0.75f ? 1.f : 0.f;
  }
  __syncthreads();

  // ---- conv1 (rows 8h..8h+7 of 16) ----
  for (int i = 4 * tid; i < 10944; i += 4096) *(v4f*)(buf1 + i) = z4;
  __syncthreads();
  conv_stage<16,4,35,128,7, 8,4, true, true, true,19,342,true, 256>(
      binb, buf1, A.offt[0], A.mc[0], tid, 8 * h);
  __syncthreads();
  // zero buf2 (aliases binb, dead); exchange buf1 boundary rows BOTH ways:
  // own row oy=8+h; partner's row lands at oy=9-h. Swizzle bit is 0 for
  // oy=8,9 so linear copy is exact.
  for (int i = 4 * tid; i < 15488; i += 4096) *(v4f*)(buf2 + i) = z4;
  if (tid < 608) {
    int c = tid / 19, x = tid - c * 19;
    e1g[h * 608 + tid] = buf1[c * 342 + (8 + h) * 19 + x];
  }
  __threadfence();
  __syncthreads();
  sigf(flg + 0);
  waitf(flg + 0, 2);
  __syncthreads();
  if (tid < 608) {
    int c = tid / 19, x = tid - c * 19;
    buf1[c * 342 + (9 - h) * 19 + x] = e1g[hp * 608 + tid];
  }
  __syncthreads();

  // ---- conv2 (rows 4h..4h+3 of 8) ----
  conv_stage<8,3,19,32,5, 32,4, false, true, true,12,121,true, 64>(
      buf1, buf2, A.offt[1], A.mc[1], tid, 4 * h);
  __syncthreads();
  // zero buf3 (aliases buf1, dead); exchange buf2 rows oy=4+h <-> oy=5-h
  // (swizzle bit 0 for oy=4,5).
  for (int i = 4 * tid; i < 18944; i += 4096) *(v4f*)(buf3 + i) = z4;
  for (int i = tid; i < 1536; i += 1024) {
    int c = i / 12, x = i - c * 12;
    e2g[h * 1536 + i] = buf2[c * 121 + (4 + h) * 12 + x];
  }
  __threadfence();
  __syncthreads();
  sigf(flg + 1);
  waitf(flg + 1, 2);
  __syncthreads();
  for (int i = tid; i < 1536; i += 1024) {
    int c = i / 12, x = i - c * 12;
    buf2[c * 121 + (5 - h) * 12 + x] = e2g[hp * 1536 + i];
  }
  __syncthreads();

  // ---- conv3 (rows 2h..2h+1 of 4) ----
  conv_stage<4,2,12,8,3, 128,4, false, true, true,6,37,false, 16>(
      buf2, buf3, A.offt[2], A.mc[2], tid, 2 * h);
  __syncthreads();
  // exchange buf3 rows oy=2+h <-> oy=3-h (no swizzle).
  for (int i = tid; i < 3072; i += 1024) {
    int c = i / 6, x = i - c * 6;
    e3g[h * 3072 + i] = buf3[c * 37 + (2 + h) * 6 + x];
  }
  __threadfence();
  __syncthreads();
  sigf(flg + 2);
  waitf(flg + 2, 2);
  __syncthreads();
  for (int i = tid; i < 3072; i += 1024) {
    int c = i / 6, x = i - c * 6;
    buf3[c * 37 + (3 - h) * 6 + x] = e3g[hp * 3072 + i];
  }
  __syncthreads();

  // ---- conv4 (row h of 2) -> h4 (flat, aliases buf2 region, dead) ----
  conv_stage<2,1,6,2,1, 512,2, false, false, false,1,4,false, 4>(
      buf3, h4, A.offt[3], A.mc[3], tid, h);
  __syncthreads();
  // bidirectional h4 exchange: 2048 elements per half, 1024 threads -> 2 passes
  #pragma unroll
  for (int g = 0; g < 2; ++g) {
    int t2 = tid + 1024 * g;
    int c = t2 >> 1, j = t2 & 1;
    e4g[h * 2048 + t2] = h4[c * 4 + 2 * h + j];
  }
  __threadfence();
  __syncthreads();
  sigf(flg + 3);
  waitf(flg + 3, 2);
  __syncthreads();
  #pragma unroll
  for (int g = 0; g < 2; ++g) {
    int t2 = tid + 1024 * g;
    int c = t2 >> 1, j = t2 & 1;
    h4[c * 4 + 2 * hp + j] = e4g[hp * 2048 + t2];
  }
  __syncthreads();

  // ---- logic1: rows [h*20480, +20480) -> g1h ----
  {
    const v4i* a4 = (const v4i*)A.la[0];
    const v4i* b4 = (const v4i*)A.lb[0];
    const v4f* w4 = (const v4f*)A.mlw[0];
    #pragma unroll 2
    for (int g = 0; g < 5; ++g) {
      int q = h * 5120 + tid + 1024 * g;
      v4i ai = a4[q], bi = b4[q];
      float r[4];
      #pragma unroll
      for (int i = 0; i < 4; ++i) {
        v4f w = w4[4 * q + i];
        float a = h4[ai[i]], bb = h4[bi[i]];
        r[i] = fmaf(w.w, a * bb, fmaf(w.z, bb, fmaf(w.y, a, w.x)));
      }
      union { __half2 hh[2]; uint2 u; } P;
      P.hh[0] = __floats2half2_rn(r[0], r[1]);
      P.hh[1] = __floats2half2_rn(r[2], r[3]);
      *(uint2*)(g1h + 4 * q) = P.u;
    }
  }
  __syncthreads();
  // bidirectional g1 exchange (dwords)
  {
    float* g1f = (float*)g1h;
    #pragma unroll
    for (int g = 0; g < 10; ++g) { int i = tid + 1024 * g; eg1g[h * 10240 + i] = g1f[h * 10240 + i]; }
    __threadfence();
    __syncthreads();
    sigf(flg + 4);
    waitf(flg + 4, 2);
    __syncthreads();
    #pragma unroll
    for (int g = 0; g < 10; ++g) { int i = tid + 1024 * g; g1f[hp * 10240 + i] = eg1g[hp * 10240 + i]; }
  }
  __syncthreads();

  // ---- logic2: rows [h*10240, +10240) -> g2h ----
  {
    const v4i* a4 = (const v4i*)A.la[1];
    const v4i* b4 = (const v4i*)A.lb[1];
    const v4f* w4 = (const v4f*)A.mlw[1];
    #pragma unroll 2
    for (int g = 0; g < 3; ++g) {
      int qr = tid + 1024 * g;
      if (qr < 2560) {
        int q = h * 2560 + qr;
        v4i ai = a4[q], bi = b4[q];
        float r[4];
        #pragma unroll
        for (int i = 0; i < 4; ++i) {
          v4f w = w4[4 * q + i];
          float a = __half2float(g1h[ai[i]]), bb = __half2float(g1h[bi[i]]);
          r[i] = fmaf(w.w, a * bb, fmaf(w.z, bb, fmaf(w.y, a, w.x)));
        }
        union { __half2 hh[2]; uint2 u; } P;
        P.hh[0] = __floats2half2_rn(r[0], r[1]);
        P.hh[1] = __floats2half2_rn(r[2], r[3]);
        *(uint2*)(g2h + 4 * q) = P.u;
      }
    }
  }
  __syncthreads();
  // bidirectional g2 exchange (dwords)
  {
    float* g2f = (float*)g2h;
    #pragma unroll
    for (int g = 0; g < 5; ++g) { int i = tid + 1024 * g; eg2g[h * 5120 + i] = g2f[h * 5120 + i]; }
    __threadfence();
    __syncthreads();
    sigf(flg + 5);
    waitf(flg + 5, 2);
    __syncthreads();
    #pragma unroll
    for (int g = 0; g < 5; ++g) { int i = tid + 1024 * g; g2f[hp * 5120 + i] = eg2g[hp * 5120 + i]; }
  }
  __syncthreads();

  // ---- logic3 + group-sum: q in [h*1280, +1280) -> classes [5h, 5h+5) ----
  {
    const v4i* a4 = (const v4i*)A.la[2];
    const v4i* b4 = (const v4i*)A.lb[2];
    const v4f* w4 = (const v4f*)A.mlw[2];
    int lane = tid & 63;
    #pragma unroll
    for (int g = 0; g < 2; ++g) {
      int qr = tid + 1024 * g;
      if (qr < 1280) {
        int q = h * 1280 + qr;
        v4i ai = a4[q], bi = b4[q];
        float s = 0.f;
        #pragma unroll
        for (int i = 0; i < 4; ++i) {
          v4f w = w4[4 * q + i];
          float a = __half2float(g2h[ai[i]]), bb = __half2float(g2h[bi[i]]);
          s += fmaf(w.w, a * bb, fmaf(w.z, bb, fmaf(w.y, a, w.x)));
        }
        #pragma unroll
        for (int m = 1; m < 64; m <<= 1) s += __shfl_xor(s, m);
        if (lane == 0) atomicAdd(&lsum[q >> 8], s);
      }
    }
  }
  __syncthreads();
  if (tid < 5) A.out[b * 10 + 5 * h + tid] = lsum[5 * h + tid] * 0.01f;
}

extern "C" void kernel_launch(void* const* d_in, const int* in_sizes, int n_in,
                              void* d_out, int out_size, void* d_ws, size_t ws_size,
                              hipStream_t stream) {
  const float* x   = (const float*)d_in[0];
  const int*   c1i = (const int*)d_in[1];
  const float* c1w = (const float*)d_in[2];
  const int*   c2i = (const int*)d_in[3];
  const float* c2w = (const float*)d_in[4];
  const int*   c3i = (const int*)d_in[5];
  const float* c3w = (const float*)d_in[6];
  const int*   c4i = (const int*)d_in[7];
  const float* c4w = (const float*)d_in[8];
  const int*   l1a = (const int*)d_in[9];
  const int*   l1b = (const int*)d_in[10];
  const float* l1w = (const float*)d_in[11];
  const int*   l2a = (const int*)d_in[12];
  const int*   l2b = (const int*)d_in[13];
  const float* l2w = (const float*)d_in[14];
  const int*   l3a = (const int*)d_in[15];
  const int*   l3b = (const int*)d_in[16];
  const float* l3w = (const float*)d_in[17];

  float* ws = (float*)d_ws;
  float* mc1 = ws;               // 224*4
  float* mc2 = mc1 + 896;        // 896*4
  float* mc3 = mc2 + 3584;       // 3584*4
  float* mc4 = mc3 + 14336;      // 7168*4
  float* ml1 = mc4 + 28672;      // 40960*4
  float* ml2 = ml1 + 163840;     // 20480*4
  float* ml3 = ml2 + 81920;      // 10240*4
  int* off1 = (int*)(ml3 + 40960);   // 32*8
  int* off2 = off1 + 256;            // 128*8
  int* off3 = off2 + 1024;           // 512*8
  int* off4 = off3 + 4096;           // 1024*8
  int* flags = off4 + 8192;          // 128*8
  float* ex = (float*)(flags + 1024); // 128*46080

  PrepArgs P;
  P.logits[0] = c1w; P.outm[0] = mc1;
  P.logits[1] = c2w; P.outm[1] = mc2;
  P.logits[2] = c3w; P.outm[2] = mc3;
  P.logits[3] = c4w; P.outm[3] = mc4;
  P.logits[4] = l1w; P.outm[4] = ml1;
  P.logits[5] = l2w; P.outm[5] = ml2;
  P.logits[6] = l3w; P.outm[6] = ml3;
  P.cidx[0] = c1i; P.offt[0] = off1;
  P.cidx[1] = c2i; P.offt[1] = off2;
  P.cidx[2] = c3i; P.offt[2] = off3;
  P.cidx[3] = c4i; P.offt[3] = off4;
  P.flags = flags;
  prep_k<<<337, 256, 0, stream>>>(P);

  MegaArgs M;
  M.x = x;
  M.mc[0] = mc1; M.mc[1] = mc2; M.mc[2] = mc3; M.mc[3] = mc4;
  M.offt[0] = off1; M.offt[1] = off2; M.offt[2] = off3; M.offt[3] = off4;
  M.la[0] = l1a; M.lb[0] = l1b; M.mlw[0] = ml1;
  M.la[1] = l2a; M.lb[1] = l2b; M.mlw[1] = ml2;
  M.la[2] = l3a; M.lb[2] = l3b; M.mlw[2] = ml3;
  M.flags = flags;
  M.ex = ex;
  M.out = (float*)d_out;

  static bool attr_set = false;
  if (!attr_set) {
    hipFuncSetAttribute((const void*)mega_k,
                        hipFuncAttributeMaxDynamicSharedMemorySize, 139328);
    attr_set = true;
  }
  mega_k<<<256, 1024, 139328, stream>>>(M);
}

// Round 10
// 169.820 us; speedup vs baseline: 3.5222x; 3.5222x over previous
//
#include <hip/hip_runtime.h>
#include <hip/hip_fp16.h>

typedef float v2f __attribute__((ext_vector_type(2)));
typedef float v4f __attribute__((ext_vector_type(4)));
typedef int   v4i __attribute__((ext_vector_type(4)));

__device__ __constant__ float GC[16][4] = {
  {0,0,0,0},{0,0,0,1},{0,1,0,-1},{0,1,0,0},
  {0,0,1,-1},{0,0,1,0},{0,1,1,-2},{0,1,1,-1},
  {1,-1,-1,1},{1,-1,-1,2},{1,0,-1,0},{1,0,-1,1},
  {1,-1,0,0},{1,-1,0,1},{1,0,0,-1},{1,0,0,0}};

// ---- packed fp32 helpers (V_PK_FMA/MUL exist on gfx950) ----
__device__ __forceinline__ v2f pk_mul(v2f a, v2f b) {
  v2f d;
  asm("v_pk_mul_f32 %0, %1, %2" : "=v"(d) : "v"(a), "v"(b));
  return d;
}
// r = w0 + w1*a + w2*b + w3*(a*b), per half; w01=(w0,w1) pair, w23=(w2,w3).
__device__ __forceinline__ v2f gate2pk(v2f a, v2f b, v2f w01, v2f w23) {
  v2f t = pk_mul(a, b);
  v2f d;
  asm("v_pk_fma_f32 %0, %1, %2, %2 op_sel:[0,1,0] op_sel_hi:[1,1,0]"
      : "=v"(d) : "v"(a), "v"(w01));
  asm("v_pk_fma_f32 %0, %1, %2, %0 op_sel:[0,0,0] op_sel_hi:[1,0,1]"
      : "+v"(d) : "v"(b), "v"(w23));
  asm("v_pk_fma_f32 %0, %1, %2, %0 op_sel:[0,1,0] op_sel_hi:[1,1,1]"
      : "+v"(d) : "v"(t), "v"(w23));
  return d;
}

__device__ __forceinline__ v2f h2f(__half2 h) {
  float2 f = __half22float2(h);
  return v2f{f.x, f.y};
}

__device__ __forceinline__ void mix_one(const float* lp, float* op) {
  float e[16];
  float s = 0.f;
  #pragma unroll
  for (int i = 0; i < 16; ++i) { e[i] = __expf(lp[i]); s += e[i]; }
  float inv = 1.0f / s;
  float w0 = 0.f, w1 = 0.f, w2 = 0.f, w3 = 0.f;
  #pragma unroll
  for (int i = 0; i < 16; ++i) {
    float p = e[i] * inv;
    w0 = fmaf(p, GC[i][0], w0);
    w1 = fmaf(p, GC[i][1], w1);
    w2 = fmaf(p, GC[i][2], w2);
    w3 = fmaf(p, GC[i][3], w3);
  }
  op[0] = w0; op[1] = w1; op[2] = w2; op[3] = w3;
}

struct PrepArgs {
  const float* logits[7];
  float* outm[7];
  const int* cidx[4];
  int* offt[4];
};

// gid 0..83551: weight softmax-mix -> 4 coefs/row.
// gid 83552..85247: decode leaf indices into LDS *element* offsets (elements
// are 4B paired-half2 cells; arithmetic identical to the f32 layout).
//  L0 binb: rows 35, CS 1190, parity swizzle
//  L1 buf1: rows 19, CS 342,  parity swizzle
//  L2 buf2: rows 12, CS 121,  parity swizzle
//  L3 buf3: rows 6,  CS 37 (odd -> random channels hash all banks)
__global__ __launch_bounds__(256) void prep_k(PrepArgs A) {
  int gid = blockIdx.x * 256 + threadIdx.x;
  if (gid < 83552) {
    const int n[7] = {224, 896, 3584, 7168, 40960, 20480, 10240};
    int g = gid, seg = 0;
    while (seg < 6 && g >= n[seg]) { g -= n[seg]; ++seg; }
    mix_one(A.logits[seg] + (size_t)g * 16, A.outm[seg] + (size_t)g * 4);
  } else if (gid < 85248) {
    int r = gid - 83552;
    int L, rr;
    if (r < 32)       { L = 0; rr = r;       }
    else if (r < 160) { L = 1; rr = r - 32;  }
    else if (r < 672) { L = 2; rr = r - 160; }
    else              { L = 3; rr = r - 672; }
    const int W2Pt[4] = {35, 19, 12, 6};
    const int CSt[4]  = {1190, 342, 121, 37};
    const int swzt[4] = {1, 1, 1, 0};
    int W2P = W2Pt[L], CS = CSt[L], swz = swzt[L];
    const int* ci = A.cidx[L] + rr * 8;
    int* oo = A.offt[L] + rr * 8;
    #pragma unroll
    for (int l = 0; l < 8; ++l) {
      int idx = ci[l];
      int c  = idx / 9;
      int k  = idx - 9 * c;
      int di = k / 3 - 1;
      int dj = k - 3 * (k / 3) - 1;
      int yl = 1 + di;                      // 0..2
      int off = c * CS + yl * W2P + 1 + dj;
      if (swz)
        off |= (((yl >> 1) & 1) << 28) | ((((yl + 1) >> 1) & 1) << 29);
      oo[l] = off;
    }
  }
}

struct MegaArgs {
  const float* x;
  const float* mc[4];    // mixed conv weights (OC x 28)
  const int*   offt[4];  // decoded leaf offsets (OC x 8)
  const int*   la[3];
  const int*   lb[3];
  const float* mlw[3];   // mixed logic weights (N x 4)
  float* out;
};

extern __shared__ char S[];

// One conv+or_pool layer. Input buffers are paired-half2: element (y,x) is a
// 4B __half2 holding (v[y][x], v[y][x+1]) -> ONE ds_read_b32 per leaf per row
// delivers both pool-window columns. Output (when OHALO) written as two
// ds_write_b16: elem[ox].x and elem[ox-1].y. Zero halo -> no bounds checks;
// row-parity swizzle (same arithmetic as f32 layout) -> conflict-reduced.
template<int OH, int OW, int LOGOW, int IW2P, int PIXCNT, int LOGPIX,
         int NCH, int ITERS, bool UNI, bool RSWZ, bool OHALO, int OW2P,
         int OCS, bool OSWZ, bool FOUT>
__device__ __forceinline__ void conv_stage(
    const __half2* in, void* outb,
    const int* __restrict__ offt, const float* __restrict__ mtab, int tid) {
  int pix = tid & (PIXCNT - 1);
  int ch0 = tid >> LOGPIX;
  int pw  = pix & (OW - 1);
  int ph  = pix >> LOGOW;
  int pixbase = 2 * ph * IW2P + 2 * pw;
  int ph1 = ph & 1;
  #pragma unroll 4
  for (int it = 0; it < ITERS; ++it) {
    int ch = ch0 + NCH * it;
    if (UNI) ch = __builtin_amdgcn_readfirstlane(ch);
    const int* ot = offt + ch * 8;
    const float* mt = mtab + ch * 28;
    v4f g0 = *(const v4f*)(mt +  0);
    v4f g1 = *(const v4f*)(mt +  4);
    v4f g2 = *(const v4f*)(mt +  8);
    v4f g3 = *(const v4f*)(mt + 12);
    v4f g4 = *(const v4f*)(mt + 16);
    v4f g5 = *(const v4f*)(mt + 20);
    v4f g6 = *(const v4f*)(mt + 24);
    v2f v01[8], v23[8];
    #pragma unroll
    for (int l = 0; l < 8; ++l) {
      int e = ot[l];
      int at, ab;
      if (RSWZ) {
        int off = e & 0x0FFFFFFF;
        at = off + pixbase + ((ph1 ^ (e >> 28)) & 1);
        ab = off + pixbase + IW2P + ((ph1 ^ (e >> 29)) & 1);
      } else {
        at = e + pixbase;
        ab = at + IW2P;
      }
      v01[l] = h2f(in[at]);
      v23[l] = h2f(in[ab]);
    }
    v2f u0 = gate2pk(v01[0], v01[1], g0.xy, g0.zw);
    v2f u1 = gate2pk(v01[2], v01[3], g1.xy, g1.zw);
    v2f u2 = gate2pk(v01[4], v01[5], g2.xy, g2.zw);
    v2f u3 = gate2pk(v01[6], v01[7], g3.xy, g3.zw);
    v2f s0 = gate2pk(u0, u1, g4.xy, g4.zw);
    v2f s1 = gate2pk(u2, u3, g5.xy, g5.zw);
    v2f r0 = gate2pk(s0, s1, g6.xy, g6.zw);
    u0 = gate2pk(v23[0], v23[1], g0.xy, g0.zw);
    u1 = gate2pk(v23[2], v23[3], g1.xy, g1.zw);
    u2 = gate2pk(v23[4], v23[5], g2.xy, g2.zw);
    u3 = gate2pk(v23[6], v23[7], g3.xy, g3.zw);
    s0 = gate2pk(u0, u1, g4.xy, g4.zw);
    s1 = gate2pk(u2, u3, g5.xy, g5.zw);
    v2f r1 = gate2pk(s0, s1, g6.xy, g6.zw);
    float res = fmaxf(fmaxf(r0.x, r0.y), fmaxf(r1.x, r1.y));
    if (OHALO) {
      int oy = 1 + ph;
      int widx = ch * OCS + oy * OW2P + 1 + pw;
      if (OSWZ) widx += (oy >> 1) & 1;
      __half hv = __float2half(res);
      __half* ob = (__half*)outb;
      ob[2 * widx] = hv;        // elem[ox].x
      ob[2 * widx - 1] = hv;    // elem[ox-1].y
    } else if (FOUT) {
      ((float*)outb)[ch * (OH * OW) + pix] = res;
    }
  }
}

// LDS layout (bytes), regions A@0 (61952) and B@61952 (75776):
//  binb [9][34][35]+pad h2 @ A      (42848)
//  buf1 [32][342] h2       @ B      (43776)
//  buf2 [128][121] h2      @ A      (61952)
//  buf3 [512][37] h2       @ B      (75776)  ends 137728
//  h4   [4096] f32         @ 0      (16384)
//  g1h  [40960] f16        @ 16384  ends 98304
//  g2h  [20480] f16        @ 98304  ends 139264
//  lsum [10] f32           @ 139264
__global__ __launch_bounds__(1024) void mega_k(MegaArgs A) {
  int tid = threadIdx.x;
  int b = blockIdx.x;
  __half2* binb = (__half2*)(S);
  __half2* buf1 = (__half2*)(S + 61952);
  __half2* buf2 = (__half2*)(S);
  __half2* buf3 = (__half2*)(S + 61952);
  float* h4   = (float*)(S);
  __half* g1h = (__half*)(S + 16384);
  __half* g2h = (__half*)(S + 98304);
  float* lsum = (float*)(S + 139264);
  const v4f z4 = {0.f, 0.f, 0.f, 0.f};

  // ---- binarize into zero-halo'd, row-swizzled, paired binb ----
  for (int i = 4 * tid; i < 10712; i += 4096) *(v4f*)((float*)binb + i) = z4;
  if (tid < 10) lsum[tid] = 0.f;
  __syncthreads();
  const float* xb = A.x + (size_t)b * 3072;
  __half* binh = (__half*)binb;
  #pragma unroll
  for (int i = 0; i < 3; ++i) {
    int idx = tid + 1024 * i;
    float v = xb[idx];
    int rgb = idx >> 10;
    int rem = idx & 1023;
    int y = rem >> 5, xx = rem & 31;
    int oy = 1 + y;
    int base = oy * 35 + 1 + xx + ((oy >> 1) & 1);
    #pragma unroll
    for (int t = 0; t < 3; ++t) {
      float th = 0.25f * (float)(t + 1);
      __half hv = __float2half(v > th ? 1.f : 0.f);
      int e = (3 * t + rgb) * 1190 + base;
      binh[2 * e] = hv;        // elem[x].lo
      binh[2 * e - 1] = hv;    // elem[x-1].hi
    }
  }
  __syncthreads();

  // ---- conv1: binb -> buf1 ----
  for (int i = 4 * tid; i < 10944; i += 4096) *(v4f*)((float*)buf1 + i) = z4;
  __syncthreads();
  conv_stage<16,16,4, 35, 256,8, 4, 8, true, true, true, 19, 342, true, false>(
      binb, buf1, A.offt[0], A.mc[0], tid);
  __syncthreads();
  // ---- conv2: buf1 -> buf2 ----
  for (int i = 4 * tid; i < 15488; i += 4096) *(v4f*)((float*)buf2 + i) = z4;
  __syncthreads();
  conv_stage<8,8,3, 19, 64,6, 16, 8, true, true, true, 12, 121, true, false>(
      buf1, buf2, A.offt[1], A.mc[1], tid);
  __syncthreads();
  // ---- conv3: buf2 -> buf3 (odd channel stride 37) ----
  for (int i = 4 * tid; i < 18944; i += 4096) *(v4f*)((float*)buf3 + i) = z4;
  __syncthreads();
  conv_stage<4,4,2, 12, 16,4, 64, 8, false, true, true, 6, 37, false, false>(
      buf2, buf3, A.offt[2], A.mc[2], tid);
  __syncthreads();
  // ---- conv4: buf3 -> h4 (flat f32, no halo) ----
  conv_stage<2,2,1, 6, 4,2, 256, 4, false, false, false, 1, 4, false, true>(
      buf3, h4, A.offt[3], A.mc[3], tid);
  __syncthreads();

  // ---- logic1: h4(f32) -> g1h(f16), 40960 rows, packed b64 stores ----
  {
    const v4i* a4 = (const v4i*)A.la[0];
    const v4i* b4 = (const v4i*)A.lb[0];
    const v4f* w4 = (const v4f*)A.mlw[0];
    #pragma unroll 2
    for (int g = 0; g < 10; ++g) {
      int q = tid + 1024 * g;
      v4i ai = a4[q], bi = b4[q];
      float r[4];
      #pragma unroll
      for (int i = 0; i < 4; ++i) {
        v4f w = w4[4 * q + i];
        float a = h4[ai[i]], bb = h4[bi[i]];
        r[i] = fmaf(w.w, a * bb, fmaf(w.z, bb, fmaf(w.y, a, w.x)));
      }
      union { __half2 hh[2]; uint2 u; } P;
      P.hh[0] = __floats2half2_rn(r[0], r[1]);
      P.hh[1] = __floats2half2_rn(r[2], r[3]);
      *(uint2*)(g1h + 4 * q) = P.u;
    }
  }
  __syncthreads();
  // ---- logic2: g1h -> g2h, 20480 rows ----
  {
    const v4i* a4 = (const v4i*)A.la[1];
    const v4i* b4 = (const v4i*)A.lb[1];
    const v4f* w4 = (const v4f*)A.mlw[1];
    #pragma unroll 2
    for (int g = 0; g < 5; ++g) {
      int q = tid + 1024 * g;
      v4i ai = a4[q], bi = b4[q];
      float r[4];
      #pragma unroll
      for (int i = 0; i < 4; ++i) {
        v4f w = w4[4 * q + i];
        float a = __half2float(g1h[ai[i]]), bb = __half2float(g1h[bi[i]]);
        r[i] = fmaf(w.w, a * bb, fmaf(w.z, bb, fmaf(w.y, a, w.x)));
      }
      union { __half2 hh[2]; uint2 u; } P;
      P.hh[0] = __floats2half2_rn(r[0], r[1]);
      P.hh[1] = __floats2half2_rn(r[2], r[3]);
      *(uint2*)(g2h + 4 * q) = P.u;
    }
  }
  __syncthreads();
  // ---- logic3 + group-sum: g2h -> per-class sums ----
  // q in [0,2560); 64 consecutive q per wave lie in one class (256 q/class)
  // -> wave shuffle-reduce, lane0 does one LDS atomic.
  {
    const v4i* a4 = (const v4i*)A.la[2];
    const v4i* b4 = (const v4i*)A.lb[2];
    const v4f* w4 = (const v4f*)A.mlw[2];
    int lane = tid & 63;
    #pragma unroll
    for (int g = 0; g < 3; ++g) {
      int q = tid + 1024 * g;
      if (q < 2560) {                       // whole waves uniform
        v4i ai = a4[q], bi = b4[q];
        float s = 0.f;
        #pragma unroll
        for (int i = 0; i < 4; ++i) {
          v4f w = w4[4 * q + i];
          float a = __half2float(g2h[ai[i]]), bb = __half2float(g2h[bi[i]]);
          s += fmaf(w.w, a * bb, fmaf(w.z, bb, fmaf(w.y, a, w.x)));
        }
        #pragma unroll
        for (int m = 1; m < 64; m <<= 1) s += __shfl_xor(s, m);
        if (lane == 0) atomicAdd(&lsum[q >> 8], s);
      }
    }
  }
  __syncthreads();
  if (tid < 10) A.out[b * 10 + tid] = lsum[tid] * 0.01f;
}

extern "C" void kernel_launch(void* const* d_in, const int* in_sizes, int n_in,
                              void* d_out, int out_size, void* d_ws, size_t ws_size,
                              hipStream_t stream) {
  const float* x   = (const float*)d_in[0];
  const int*   c1i = (const int*)d_in[1];
  const float* c1w = (const float*)d_in[2];
  const int*   c2i = (const int*)d_in[3];
  const float* c2w = (const float*)d_in[4];
  const int*   c3i = (const int*)d_in[5];
  const float* c3w = (const float*)d_in[6];
  const int*   c4i = (const int*)d_in[7];
  const float* c4w = (const float*)d_in[8];
  const int*   l1a = (const int*)d_in[9];
  const int*   l1b = (const int*)d_in[10];
  const float* l1w = (const float*)d_in[11];
  const int*   l2a = (const int*)d_in[12];
  const int*   l2b = (const int*)d_in[13];
  const float* l2w = (const float*)d_in[14];
  const int*   l3a = (const int*)d_in[15];
  const int*   l3b = (const int*)d_in[16];
  const float* l3w = (const float*)d_in[17];

  float* ws = (float*)d_ws;
  float* mc1 = ws;               // 224*4
  float* mc2 = mc1 + 896;        // 896*4
  float* mc3 = mc2 + 3584;       // 3584*4
  float* mc4 = mc3 + 14336;      // 7168*4
  float* ml1 = mc4 + 28672;      // 40960*4
  float* ml2 = ml1 + 163840;     // 20480*4
  float* ml3 = ml2 + 81920;      // 10240*4
  int* off1 = (int*)(ml3 + 40960);   // 32*8
  int* off2 = off1 + 256;            // 128*8
  int* off3 = off2 + 1024;           // 512*8
  int* off4 = off3 + 4096;           // 1024*8

  PrepArgs P;
  P.logits[0] = c1w; P.outm[0] = mc1;
  P.logits[1] = c2w; P.outm[1] = mc2;
  P.logits[2] = c3w; P.outm[2] = mc3;
  P.logits[3] = c4w; P.outm[3] = mc4;
  P.logits[4] = l1w; P.outm[4] = ml1;
  P.logits[5] = l2w; P.outm[5] = ml2;
  P.logits[6] = l3w; P.outm[6] = ml3;
  P.cidx[0] = c1i; P.offt[0] = off1;
  P.cidx[1] = c2i; P.offt[1] = off2;
  P.cidx[2] = c3i; P.offt[2] = off3;
  P.cidx[3] = c4i; P.offt[3] = off4;
  prep_k<<<333, 256, 0, stream>>>(P);

  MegaArgs M;
  M.x = x;
  M.mc[0] = mc1; M.mc[1] = mc2; M.mc[2] = mc3; M.mc[3] = mc4;
  M.offt[0] = off1; M.offt[1] = off2; M.offt[2] = off3; M.offt[3] = off4;
  M.la[0] = l1a; M.lb[0] = l1b; M.mlw[0] = ml1;
  M.la[1] = l2a; M.lb[1] = l2b; M.mlw[1] = ml2;
  M.la[2] = l3a; M.lb[2] = l3b; M.mlw[2] = ml3;
  M.out = (float*)d_out;

  static bool attr_set = false;
  if (!attr_set) {
    hipFuncSetAttribute((const void*)mega_k,
                        hipFuncAttributeMaxDynamicSharedMemorySize, 139328);
    attr_set = true;
  }
  mega_k<<<128, 1024, 139328, stream>>>(M);
}

// Round 11
// 154.663 us; speedup vs baseline: 3.8674x; 1.0980x over previous
//
#include <hip/hip_runtime.h>
#include <hip/hip_fp16.h>

typedef float v2f __attribute__((ext_vector_type(2)));
typedef float v4f __attribute__((ext_vector_type(4)));
typedef int   v4i __attribute__((ext_vector_type(4)));

__device__ __constant__ float GC[16][4] = {
  {0,0,0,0},{0,0,0,1},{0,1,0,-1},{0,1,0,0},
  {0,0,1,-1},{0,0,1,0},{0,1,1,-2},{0,1,1,-1},
  {1,-1,-1,1},{1,-1,-1,2},{1,0,-1,0},{1,0,-1,1},
  {1,-1,0,0},{1,-1,0,1},{1,0,0,-1},{1,0,0,0}};

// ---- packed fp32 helpers (V_PK_FMA/MUL exist on gfx950) ----
__device__ __forceinline__ v2f pk_mul(v2f a, v2f b) {
  v2f d;
  asm("v_pk_mul_f32 %0, %1, %2" : "=v"(d) : "v"(a), "v"(b));
  return d;
}
// r = w0 + w1*a + w2*b + w3*(a*b), per half; w01=(w0,w1) pair, w23=(w2,w3).
__device__ __forceinline__ v2f gate2pk(v2f a, v2f b, v2f w01, v2f w23) {
  v2f t = pk_mul(a, b);
  v2f d;
  asm("v_pk_fma_f32 %0, %1, %2, %2 op_sel:[0,1,0] op_sel_hi:[1,1,0]"
      : "=v"(d) : "v"(a), "v"(w01));
  asm("v_pk_fma_f32 %0, %1, %2, %0 op_sel:[0,0,0] op_sel_hi:[1,0,1]"
      : "+v"(d) : "v"(b), "v"(w23));
  asm("v_pk_fma_f32 %0, %1, %2, %0 op_sel:[0,1,0] op_sel_hi:[1,1,1]"
      : "+v"(d) : "v"(t), "v"(w23));
  return d;
}

__device__ __forceinline__ void mix_one(const float* lp, float* op) {
  // logits are 0.01*N(0,1) (+5 on slot 3): exp() safe without max-shift
  float e[16];
  float s = 0.f;
  #pragma unroll
  for (int i = 0; i < 16; ++i) { e[i] = __expf(lp[i]); s += e[i]; }
  float inv = 1.0f / s;
  float w0 = 0.f, w1 = 0.f, w2 = 0.f, w3 = 0.f;
  #pragma unroll
  for (int i = 0; i < 16; ++i) {
    float p = e[i] * inv;
    w0 = fmaf(p, GC[i][0], w0);
    w1 = fmaf(p, GC[i][1], w1);
    w2 = fmaf(p, GC[i][2], w2);
    w3 = fmaf(p, GC[i][3], w3);
  }
  op[0] = w0; op[1] = w1; op[2] = w2; op[3] = w3;
}

struct PrepArgs {
  const float* logits[7];
  float* outm[7];
  const int* cidx[4];
  int* offt[4];
};

// gid 0..83551: weight softmax-mix -> 4 coefs/row.
// gid 83552..85247: decode leaf indices into LDS element offsets relative to
// zero-halo'd buffers. Strides chosen for bank-conflict freedom:
//  L0 binb: rows 35, CS 1190, parity swizzle
//  L1 buf1: rows 19, CS 342,  parity swizzle
//  L2 buf2: rows 12, CS 121 (odd -> conv3 channel subgroups mix parity), swz
//  L3 buf3: rows 6,  CS 37 (odd -> random channels hash all 32 banks)
__global__ __launch_bounds__(256) void prep_k(PrepArgs A) {
  int gid = blockIdx.x * 256 + threadIdx.x;
  if (gid < 83552) {
    const int n[7] = {224, 896, 3584, 7168, 40960, 20480, 10240};
    int g = gid, seg = 0;
    while (seg < 6 && g >= n[seg]) { g -= n[seg]; ++seg; }
    mix_one(A.logits[seg] + (size_t)g * 16, A.outm[seg] + (size_t)g * 4);
  } else if (gid < 85248) {
    int r = gid - 83552;
    int L, rr;
    if (r < 32)       { L = 0; rr = r;       }
    else if (r < 160) { L = 1; rr = r - 32;  }
    else if (r < 672) { L = 2; rr = r - 160; }
    else              { L = 3; rr = r - 672; }
    const int W2Pt[4] = {35, 19, 12, 6};
    const int CSt[4]  = {1190, 342, 121, 37};
    const int swzt[4] = {1, 1, 1, 0};
    int W2P = W2Pt[L], CS = CSt[L], swz = swzt[L];
    const int* ci = A.cidx[L] + rr * 8;
    int* oo = A.offt[L] + rr * 8;
    #pragma unroll
    for (int l = 0; l < 8; ++l) {
      int idx = ci[l];
      int c  = idx / 9;
      int k  = idx - 9 * c;
      int di = k / 3 - 1;
      int dj = k - 3 * (k / 3) - 1;
      int yl = 1 + di;                      // 0..2
      int off = c * CS + yl * W2P + 1 + dj;
      if (swz)
        off |= (((yl >> 1) & 1) << 28) | ((((yl + 1) >> 1) & 1) << 29);
      oo[l] = off;
    }
  }
}

struct MegaArgs {
  const float* x;
  const float* mc[4];    // mixed conv weights (OC x 28)
  const int*   offt[4];  // decoded leaf offsets (OC x 8)
  const int*   la[3];
  const int*   lb[3];
  const float* mlw[3];   // mixed logic weights (N x 4)
  float* out;
};

extern __shared__ char S[];

// One conv+or_pool layer, input/output in LDS (zero halo -> no bounds checks,
// row swizzle / stride choice -> bank-conflict-reduced stride-2 lane access).
template<int OH, int OW, int LOGOW, int IW2P, int PIXCNT, int LOGPIX,
         int NCH, int ITERS, bool UNI, bool RSWZ, bool OHALO, int OW2P,
         int OCS, bool OSWZ>
__device__ __forceinline__ void conv_stage(
    const float* in, float* outb,
    const int* __restrict__ offt, const float* __restrict__ mtab, int tid) {
  int pix = tid & (PIXCNT - 1);
  int ch0 = tid >> LOGPIX;
  int pw  = pix & (OW - 1);
  int ph  = pix >> LOGOW;
  int pixbase = 2 * ph * IW2P + 2 * pw;
  int ph1 = ph & 1;
  #pragma unroll 4
  for (int it = 0; it < ITERS; ++it) {
    int ch = ch0 + NCH * it;
    if (UNI) ch = __builtin_amdgcn_readfirstlane(ch);
    const int* ot = offt + ch * 8;
    const float* mt = mtab + ch * 28;
    v4f g0 = *(const v4f*)(mt +  0);
    v4f g1 = *(const v4f*)(mt +  4);
    v4f g2 = *(const v4f*)(mt +  8);
    v4f g3 = *(const v4f*)(mt + 12);
    v4f g4 = *(const v4f*)(mt + 16);
    v4f g5 = *(const v4f*)(mt + 20);
    v4f g6 = *(const v4f*)(mt + 24);
    v2f v01[8], v23[8];
    #pragma unroll
    for (int l = 0; l < 8; ++l) {
      int e = ot[l];
      int at, ab;
      if (RSWZ) {
        int off = e & 0x0FFFFFFF;
        at = off + pixbase + ((ph1 ^ (e >> 28)) & 1);
        ab = off + pixbase + IW2P + ((ph1 ^ (e >> 29)) & 1);
      } else {
        at = e + pixbase;
        ab = at + IW2P;
      }
      v2f t0; t0.x = in[at]; t0.y = in[at + 1];
      v2f t1; t1.x = in[ab]; t1.y = in[ab + 1];
      v01[l] = t0; v23[l] = t1;
    }
    v2f u0 = gate2pk(v01[0], v01[1], g0.xy, g0.zw);
    v2f u1 = gate2pk(v01[2], v01[3], g1.xy, g1.zw);
    v2f u2 = gate2pk(v01[4], v01[5], g2.xy, g2.zw);
    v2f u3 = gate2pk(v01[6], v01[7], g3.xy, g3.zw);
    v2f s0 = gate2pk(u0, u1, g4.xy, g4.zw);
    v2f s1 = gate2pk(u2, u3, g5.xy, g5.zw);
    v2f r0 = gate2pk(s0, s1, g6.xy, g6.zw);
    u0 = gate2pk(v23[0], v23[1], g0.xy, g0.zw);
    u1 = gate2pk(v23[2], v23[3], g1.xy, g1.zw);
    u2 = gate2pk(v23[4], v23[5], g2.xy, g2.zw);
    u3 = gate2pk(v23[6], v23[7], g3.xy, g3.zw);
    s0 = gate2pk(u0, u1, g4.xy, g4.zw);
    s1 = gate2pk(u2, u3, g5.xy, g5.zw);
    v2f r1 = gate2pk(s0, s1, g6.xy, g6.zw);
    float res = fmaxf(fmaxf(r0.x, r0.y), fmaxf(r1.x, r1.y));
    if (OHALO) {
      int oy = 1 + ph;
      int widx = ch * OCS + oy * OW2P + 1 + pw;
      if (OSWZ) widx += (oy >> 1) & 1;
      outb[widx] = res;
    } else {
      outb[ch * (OH * OW) + pix] = res;
    }
  }
}

// LDS layout (bytes), two ping-pong regions A@0 (61952) and B@61952 (75776):
//  binb [9][34][35]+pad f32 @ A      (42848)
//  buf1 [32][18][19] f32    @ B      (43776)
//  buf2 [128 x 121] f32     @ A      (61952)
//  buf3 [512 x 37] f32      @ B      (75776)  ends 137728
//  h4   [4096] f32          @ 0      (16384)
//  g1h  [40960] f16         @ 16384  (81920)  ends 98304
//  g2h  [20480] f16         @ 98304  (40960)  ends 139264
//  lsum [10] f32            @ 139264
__global__ __launch_bounds__(1024) void mega_k(MegaArgs A) {
  int tid = threadIdx.x;
  int b = blockIdx.x;
  float* binb = (float*)(S);
  float* buf1 = (float*)(S + 61952);
  float* buf2 = (float*)(S);
  float* buf3 = (float*)(S + 61952);
  float* h4   = (float*)(S);
  __half* g1h = (__half*)(S + 16384);
  __half* g2h = (__half*)(S + 98304);
  float* lsum = (float*)(S + 139264);
  const v4f z4 = {0.f, 0.f, 0.f, 0.f};

  // ---- zero binb AND buf1 together (disjoint regions, one barrier) ----
  for (int i = 4 * tid; i < 10712; i += 4096) *(v4f*)(binb + i) = z4;
  for (int i = 4 * tid; i < 10944; i += 4096) *(v4f*)(buf1 + i) = z4;
  if (tid < 10) lsum[tid] = 0.f;
  __syncthreads();
  // ---- binarize into zero-halo'd, row-swizzled binb ----
  const float* xb = A.x + (size_t)b * 3072;
  #pragma unroll
  for (int i = 0; i < 3; ++i) {
    int idx = tid + 1024 * i;
    float v = xb[idx];
    int rgb = idx >> 10;
    int rem = idx & 1023;
    int y = rem >> 5, xx = rem & 31;
    int oy = 1 + y;
    int base = oy * 35 + 1 + xx + ((oy >> 1) & 1);
    binb[(0 + rgb) * 1190 + base] = v > 0.25f ? 1.f : 0.f;
    binb[(3 + rgb) * 1190 + base] = v > 0.50f ? 1.f : 0.f;
    binb[(6 + rgb) * 1190 + base] = v > 0.75f ? 1.f : 0.f;
  }
  __syncthreads();

  // ---- conv1: binb -> buf1 ----
  conv_stage<16,16,4, 35, 256,8, 4, 8, true, true, true, 19, 342, true>(
      binb, buf1, A.offt[0], A.mc[0], tid);
  __syncthreads();
  // ---- zero buf2 (aliases binb; must follow conv1's reads) ----
  for (int i = 4 * tid; i < 15488; i += 4096) *(v4f*)(buf2 + i) = z4;
  __syncthreads();
  // ---- conv2: buf1 -> buf2 ----
  conv_stage<8,8,3, 19, 64,6, 16, 8, true, true, true, 12, 121, true>(
      buf1, buf2, A.offt[1], A.mc[1], tid);
  __syncthreads();
  // ---- zero buf3 (aliases buf1; must follow conv2's reads) ----
  for (int i = 4 * tid; i < 18944; i += 4096) *(v4f*)(buf3 + i) = z4;
  __syncthreads();
  // ---- conv3: buf2 -> buf3 (odd channel stride 37, unswizzled output) ----
  conv_stage<4,4,2, 12, 16,4, 64, 8, false, true, true, 6, 37, false>(
      buf2, buf3, A.offt[2], A.mc[2], tid);
  __syncthreads();
  // ---- conv4: buf3 -> h4 (flat, full overwrite, no zero needed) ----
  conv_stage<2,2,1, 6, 4,2, 256, 4, false, false, false, 1, 4, false>(
      buf3, h4, A.offt[3], A.mc[3], tid);
  __syncthreads();

  // ---- logic1: h4(f32) -> g1h(f16), 40960 rows, packed b64 stores ----
  {
    const v4i* a4 = (const v4i*)A.la[0];
    const v4i* b4 = (const v4i*)A.lb[0];
    const v4f* w4 = (const v4f*)A.mlw[0];
    #pragma unroll 2
    for (int g = 0; g < 10; ++g) {
      int q = tid + 1024 * g;
      v4i ai = a4[q], bi = b4[q];
      float r[4];
      #pragma unroll
      for (int i = 0; i < 4; ++i) {
        v4f w = w4[4 * q + i];
        float a = h4[ai[i]], bb = h4[bi[i]];
        r[i] = fmaf(w.w, a * bb, fmaf(w.z, bb, fmaf(w.y, a, w.x)));
      }
      union { __half2 hh[2]; uint2 u; } P;
      P.hh[0] = __floats2half2_rn(r[0], r[1]);
      P.hh[1] = __floats2half2_rn(r[2], r[3]);
      *(uint2*)(g1h + 4 * q) = P.u;
    }
  }
  __syncthreads();
  // ---- logic2: g1h -> g2h, 20480 rows ----
  {
    const v4i* a4 = (const v4i*)A.la[1];
    const v4i* b4 = (const v4i*)A.lb[1];
    const v4f* w4 = (const v4f*)A.mlw[1];
    #pragma unroll 2
    for (int g = 0; g < 5; ++g) {
      int q = tid + 1024 * g;
      v4i ai = a4[q], bi = b4[q];
      float r[4];
      #pragma unroll
      for (int i = 0; i < 4; ++i) {
        v4f w = w4[4 * q + i];
        float a = __half2float(g1h[ai[i]]), bb = __half2float(g1h[bi[i]]);
        r[i] = fmaf(w.w, a * bb, fmaf(w.z, bb, fmaf(w.y, a, w.x)));
      }
      union { __half2 hh[2]; uint2 u; } P;
      P.hh[0] = __floats2half2_rn(r[0], r[1]);
      P.hh[1] = __floats2half2_rn(r[2], r[3]);
      *(uint2*)(g2h + 4 * q) = P.u;
    }
  }
  __syncthreads();
  // ---- logic3 + group-sum: g2h -> per-class sums ----
  // q in [0,2560); 64 consecutive q per wave lie in one class (256 q/class)
  // -> wave shuffle-reduce, lane0 does one LDS atomic.
  {
    const v4i* a4 = (const v4i*)A.la[2];
    const v4i* b4 = (const v4i*)A.lb[2];
    const v4f* w4 = (const v4f*)A.mlw[2];
    int lane = tid & 63;
    #pragma unroll
    for (int g = 0; g < 3; ++g) {
      int q = tid + 1024 * g;
      if (q < 2560) {                       // whole waves uniform
        v4i ai = a4[q], bi = b4[q];
        float s = 0.f;
        #pragma unroll
        for (int i = 0; i < 4; ++i) {
          v4f w = w4[4 * q + i];
          float a = __half2float(g2h[ai[i]]), bb = __half2float(g2h[bi[i]]);
          s += fmaf(w.w, a * bb, fmaf(w.z, bb, fmaf(w.y, a, w.x)));
        }
        #pragma unroll
        for (int m = 1; m < 64; m <<= 1) s += __shfl_xor(s, m);
        if (lane == 0) atomicAdd(&lsum[q >> 8], s);
      }
    }
  }
  __syncthreads();
  if (tid < 10) A.out[b * 10 + tid] = lsum[tid] * 0.01f;
}

extern "C" void kernel_launch(void* const* d_in, const int* in_sizes, int n_in,
                              void* d_out, int out_size, void* d_ws, size_t ws_size,
                              hipStream_t stream) {
  const float* x   = (const float*)d_in[0];
  const int*   c1i = (const int*)d_in[1];
  const float* c1w = (const float*)d_in[2];
  const int*   c2i = (const int*)d_in[3];
  const float* c2w = (const float*)d_in[4];
  const int*   c3i = (const int*)d_in[5];
  const float* c3w = (const float*)d_in[6];
  const int*   c4i = (const int*)d_in[7];
  const float* c4w = (const float*)d_in[8];
  const int*   l1a = (const int*)d_in[9];
  const int*   l1b = (const int*)d_in[10];
  const float* l1w = (const float*)d_in[11];
  const int*   l2a = (const int*)d_in[12];
  const int*   l2b = (const int*)d_in[13];
  const float* l2w = (const float*)d_in[14];
  const int*   l3a = (const int*)d_in[15];
  const int*   l3b = (const int*)d_in[16];
  const float* l3w = (const float*)d_in[17];

  float* ws = (float*)d_ws;
  float* mc1 = ws;               // 224*4
  float* mc2 = mc1 + 896;        // 896*4
  float* mc3 = mc2 + 3584;       // 3584*4
  float* mc4 = mc3 + 14336;      // 7168*4
  float* ml1 = mc4 + 28672;      // 40960*4
  float* ml2 = ml1 + 163840;     // 20480*4
  float* ml3 = ml2 + 81920;      // 10240*4
  int* off1 = (int*)(ml3 + 40960);   // 32*8
  int* off2 = off1 + 256;            // 128*8
  int* off3 = off2 + 1024;           // 512*8
  int* off4 = off3 + 4096;           // 1024*8

  PrepArgs P;
  P.logits[0] = c1w; P.outm[0] = mc1;
  P.logits[1] = c2w; P.outm[1] = mc2;
  P.logits[2] = c3w; P.outm[2] = mc3;
  P.logits[3] = c4w; P.outm[3] = mc4;
  P.logits[4] = l1w; P.outm[4] = ml1;
  P.logits[5] = l2w; P.outm[5] = ml2;
  P.logits[6] = l3w; P.outm[6] = ml3;
  P.cidx[0] = c1i; P.offt[0] = off1;
  P.cidx[1] = c2i; P.offt[1] = off2;
  P.cidx[2] = c3i; P.offt[2] = off3;
  P.cidx[3] = c4i; P.offt[3] = off4;
  prep_k<<<333, 256, 0, stream>>>(P);

  MegaArgs M;
  M.x = x;
  M.mc[0] = mc1; M.mc[1] = mc2; M.mc[2] = mc3; M.mc[3] = mc4;
  M.offt[0] = off1; M.offt[1] = off2; M.offt[2] = off3; M.offt[3] = off4;
  M.la[0] = l1a; M.lb[0] = l1b; M.mlw[0] = ml1;
  M.la[1] = l2a; M.lb[1] = l2b; M.mlw[1] = ml2;
  M.la[2] = l3a; M.lb[2] = l3b; M.mlw[2] = ml3;
  M.out = (float*)d_out;

  static bool attr_set = false;
  if (!attr_set) {
    hipFuncSetAttribute((const void*)mega_k,
                        hipFuncAttributeMaxDynamicSharedMemorySize, 139328);
    attr_set = true;
  }
  mega_k<<<128, 1024, 139328, stream>>>(M);
}